// Round 1
// baseline (4049.531 us; speedup 1.0000x reference)
//
#include <hip/hip_runtime.h>

// AxialAttention3D fused kernel (fp32 vector version, round 1)
// B=2, C=512, D=32, H=32, W=32, heads=8, head_dim=64

__device__ __forceinline__ float b2f(unsigned int u) {
    union { float f; unsigned int i; } x; x.i = u << 16; return x.f;
}
__device__ __forceinline__ unsigned int f2b(float f) {
    union { float f; unsigned int i; } x; x.f = f;
    unsigned int r = x.i + 0x7FFFu + ((x.i >> 16) & 1u);
    return r >> 16;
}
__device__ __forceinline__ void unpack8(uint4 v, float* f) {
    f[0] = b2f(v.x & 0xffffu); f[1] = b2f(v.x >> 16);
    f[2] = b2f(v.y & 0xffffu); f[3] = b2f(v.y >> 16);
    f[4] = b2f(v.z & 0xffffu); f[5] = b2f(v.z >> 16);
    f[6] = b2f(v.w & 0xffffu); f[7] = b2f(v.w >> 16);
}

__global__ __launch_bounds__(512, 2)
void axial3d_fused(const float* __restrict__ x,
                   const float* __restrict__ w_qkv,
                   const float* __restrict__ b_qkv,
                   const float* __restrict__ w_out,
                   const float* __restrict__ b_out,
                   float* __restrict__ out)
{
    // 64 KB fp32 x slice [c][d] + 96 KB bf16 qkv [o][d]  = exactly 160 KB
    __shared__ __align__(16) float          x_s[512][32];
    __shared__ __align__(16) unsigned short qkv_s[1536][32];

    const int bid  = blockIdx.x;
    const int work = (bid & 7) * 256 + (bid >> 3);   // XCD-contiguous (b,h) rows
    const int b    = work >> 10;
    const int h    = (work >> 5) & 31;
    const int w    = work & 31;

    const float* xb = x   + ((size_t)b * 16777216u) + h * 32 + w;
    float*       ob = out + ((size_t)b * 16777216u) + h * 32 + w;

    const int tid  = threadIdx.x;
    const int wv   = tid >> 6;     // wave id 0..7
    const int lane = tid & 63;

    // ---------------- phase 1: stage x[b,:,:,h,w] -> x_s[c][d] ----------------
    #pragma unroll
    for (int k = 0; k < 32; ++k) {
        int cd = tid + k * 512;
        ((float*)x_s)[cd] = xb[(cd >> 5) * 32768 + (cd & 31) * 1024];
    }
    __syncthreads();

    const int dg   = lane & 15;    // d-pair group: d = 2*dg, 2*dg+1
    const int d0   = dg * 2;
    const int cseg = lane >> 4;    // K-split 0..3, 128 c each

    // ---------------- phase 2: QKV GEMM -> qkv_s (bf16) ----------------
    for (int pass = 0; pass < 24; ++pass) {
        const int obase = wv * 192 + pass * 8;
        float2 acc[8];
        #pragma unroll
        for (int i = 0; i < 8; ++i) acc[i] = make_float2(0.f, 0.f);
        const float* wp = w_qkv + obase * 512 + cseg * 128;
        for (int cc4 = 0; cc4 < 32; ++cc4) {
            float4 wl[8];
            #pragma unroll
            for (int i = 0; i < 8; ++i)
                wl[i] = *(const float4*)(wp + i * 512 + cc4 * 4);
            float2 xv[4];
            #pragma unroll
            for (int u = 0; u < 4; ++u)
                xv[u] = *(const float2*)&x_s[cseg * 128 + cc4 * 4 + u][d0];
            #pragma unroll
            for (int i = 0; i < 8; ++i) {
                acc[i].x = fmaf(wl[i].x, xv[0].x, acc[i].x);
                acc[i].y = fmaf(wl[i].x, xv[0].y, acc[i].y);
                acc[i].x = fmaf(wl[i].y, xv[1].x, acc[i].x);
                acc[i].y = fmaf(wl[i].y, xv[1].y, acc[i].y);
                acc[i].x = fmaf(wl[i].z, xv[2].x, acc[i].x);
                acc[i].y = fmaf(wl[i].z, xv[2].y, acc[i].y);
                acc[i].x = fmaf(wl[i].w, xv[3].x, acc[i].x);
                acc[i].y = fmaf(wl[i].w, xv[3].y, acc[i].y);
            }
        }
        #pragma unroll
        for (int i = 0; i < 8; ++i) {
            acc[i].x += __shfl_xor(acc[i].x, 16);
            acc[i].x += __shfl_xor(acc[i].x, 32);
            acc[i].y += __shfl_xor(acc[i].y, 16);
            acc[i].y += __shfl_xor(acc[i].y, 32);
        }
        if (cseg == 0) {
            #pragma unroll
            for (int i = 0; i < 8; ++i) {
                const int o = obase + i;
                const float bias = b_qkv[o];
                unsigned int pk = f2b(acc[i].x + bias) | (f2b(acc[i].y + bias) << 16);
                ((unsigned int*)qkv_s)[o * 16 + dg] = pk;
            }
        }
    }
    __syncthreads();

    // ---------------- phase 3: attention, head = wv ----------------
    {
        const int n    = wv;
        const int qi   = lane & 31;   // depth index i
        const int jseg = lane >> 5;   // j half: 16 j's per lane

        float acc16[16];
        #pragma unroll
        for (int t = 0; t < 16; ++t) acc16[t] = 0.f;
        for (int cc = 0; cc < 64; ++cc) {            // head-dim reduction
            const float qf = b2f((unsigned int)qkv_s[n * 64 + cc][qi]);
            const uint4* kp = (const uint4*)&qkv_s[512 + n * 64 + cc][jseg * 16];
            float kf[16];
            unpack8(kp[0], kf);
            unpack8(kp[1], kf + 8);
            #pragma unroll
            for (int t = 0; t < 16; ++t) acc16[t] = fmaf(qf, kf[t], acc16[t]);
        }
        // softmax over j (scale 1/sqrt(64) = 0.125)
        float m = acc16[0];
        #pragma unroll
        for (int t = 1; t < 16; ++t) m = fmaxf(m, acc16[t]);
        m = fmaxf(m, __shfl_xor(m, 32));
        float p16[16];
        float s = 0.f;
        #pragma unroll
        for (int t = 0; t < 16; ++t) {
            p16[t] = __expf((acc16[t] - m) * 0.125f);
            s += p16[t];
        }
        s += __shfl_xor(s, 32);
        const float inv = 1.0f / s;
        unsigned int pk[8];
        #pragma unroll
        for (int u = 0; u < 8; ++u)
            pk[u] = f2b(p16[2*u] * inv) | (f2b(p16[2*u+1] * inv) << 16);
        // store P into dead Q-slot rows [n*64 .. n*64+32)
        uint4* dst = (uint4*)&qkv_s[n * 64 + qi][jseg * 16];
        dst[0] = make_uint4(pk[0], pk[1], pk[2], pk[3]);
        dst[1] = make_uint4(pk[4], pk[5], pk[6], pk[7]);

        // PV: out_attn[e][i] = sum_j P[i][j] * V[e][j]  -> dead K-slot
        float pf[32];
        {
            const uint4* pp = (const uint4*)&qkv_s[n * 64 + qi][0];
            unpack8(pp[0], pf);      unpack8(pp[1], pf + 8);
            unpack8(pp[2], pf + 16); unpack8(pp[3], pf + 24);
        }
        const int ccseg = jseg;                       // e-half per lane
        for (int cc = ccseg * 32; cc < ccseg * 32 + 32; ++cc) {
            const uint4* vp = (const uint4*)&qkv_s[1024 + n * 64 + cc][0];
            float vf[32];
            unpack8(vp[0], vf);      unpack8(vp[1], vf + 8);
            unpack8(vp[2], vf + 16); unpack8(vp[3], vf + 24);
            float s0 = 0.f, s1 = 0.f, s2 = 0.f, s3 = 0.f;
            #pragma unroll
            for (int j = 0; j < 32; j += 4) {
                s0 = fmaf(pf[j],     vf[j],     s0);
                s1 = fmaf(pf[j + 1], vf[j + 1], s1);
                s2 = fmaf(pf[j + 2], vf[j + 2], s2);
                s3 = fmaf(pf[j + 3], vf[j + 3], s3);
            }
            qkv_s[512 + n * 64 + cc][qi] = (unsigned short)f2b((s0 + s1) + (s2 + s3));
        }
    }
    __syncthreads();

    // ---------------- phase 4: out projection + bias + residual ----------------
    const unsigned int* os = (const unsigned int*)qkv_s + 512 * 16;  // attn-out rows
    for (int pass = 0; pass < 8; ++pass) {
        const int obase = wv * 64 + pass * 8;
        float2 acc[8];
        #pragma unroll
        for (int i = 0; i < 8; ++i) acc[i] = make_float2(0.f, 0.f);
        const float* wp = w_out + obase * 512 + cseg * 128;
        for (int cc4 = 0; cc4 < 32; ++cc4) {
            float4 wl[8];
            #pragma unroll
            for (int i = 0; i < 8; ++i)
                wl[i] = *(const float4*)(wp + i * 512 + cc4 * 4);
            float2 ov[4];
            #pragma unroll
            for (int u = 0; u < 4; ++u) {
                unsigned int raw = os[(cseg * 128 + cc4 * 4 + u) * 16 + dg];
                ov[u] = make_float2(b2f(raw & 0xffffu), b2f(raw >> 16));
            }
            #pragma unroll
            for (int i = 0; i < 8; ++i) {
                acc[i].x = fmaf(wl[i].x, ov[0].x, acc[i].x);
                acc[i].y = fmaf(wl[i].x, ov[0].y, acc[i].y);
                acc[i].x = fmaf(wl[i].y, ov[1].x, acc[i].x);
                acc[i].y = fmaf(wl[i].y, ov[1].y, acc[i].y);
                acc[i].x = fmaf(wl[i].z, ov[2].x, acc[i].x);
                acc[i].y = fmaf(wl[i].z, ov[2].y, acc[i].y);
                acc[i].x = fmaf(wl[i].w, ov[3].x, acc[i].x);
                acc[i].y = fmaf(wl[i].w, ov[3].y, acc[i].y);
            }
        }
        #pragma unroll
        for (int i = 0; i < 8; ++i) {
            acc[i].x += __shfl_xor(acc[i].x, 16);
            acc[i].x += __shfl_xor(acc[i].x, 32);
            acc[i].y += __shfl_xor(acc[i].y, 16);
            acc[i].y += __shfl_xor(acc[i].y, 32);
        }
        if (cseg == 0) {
            #pragma unroll
            for (int i = 0; i < 8; ++i) {
                const int o = obase + i;
                const float bias = b_out[o];
                float rx = acc[i].x + bias + x_s[o][d0];
                float ry = acc[i].y + bias + x_s[o][d0 + 1];
                ob[o * 32768 + d0 * 1024]       = rx;
                ob[o * 32768 + (d0 + 1) * 1024] = ry;
            }
        }
    }
}

extern "C" void kernel_launch(void* const* d_in, const int* in_sizes, int n_in,
                              void* d_out, int out_size, void* d_ws, size_t ws_size,
                              hipStream_t stream) {
    const float* x     = (const float*)d_in[0];
    const float* w_qkv = (const float*)d_in[1];
    const float* b_qkv = (const float*)d_in[2];
    const float* w_out = (const float*)d_in[3];
    const float* b_out = (const float*)d_in[4];
    float* out = (float*)d_out;
    axial3d_fused<<<dim3(2048), dim3(512), 0, stream>>>(x, w_qkv, b_qkv, w_out, b_out, out);
}

// Round 2
// 870.057 us; speedup vs baseline: 4.6543x; 4.6543x over previous
//
#include <hip/hip_runtime.h>

// AxialAttention3D fused MFMA kernel (round 2)
// B=2, C=512, D=32, H=32, W=32, heads=8, head_dim=64

typedef __bf16 bf16x8 __attribute__((ext_vector_type(8)));
typedef float  f32x4  __attribute__((ext_vector_type(4)));

__device__ __forceinline__ float b2f(unsigned int u) {
    union { float f; unsigned int i; } x; x.i = u << 16; return x.f;
}
__device__ __forceinline__ unsigned short f2b(float f) {
    union { float f; unsigned int i; } x; x.f = f;
    unsigned int r = x.i + 0x7FFFu + ((x.i >> 16) & 1u);
    return (unsigned short)(r >> 16);
}

__device__ __forceinline__ f32x4 mfma16(bf16x8 a, bf16x8 b, f32x4 c) {
    return __builtin_amdgcn_mfma_f32_16x16x32_bf16(a, b, c, 0, 0, 0);
}

// LDS byte-address helpers (XOR swizzle, 16B granules within 128B groups)
__device__ __forceinline__ int adr_qk(int row, int cb) {          // [32][2048B] Q|K/ao
    return row * 2048 + (cb ^ ((row & 7) << 4));
}
__device__ __forceinline__ int adr_x(int row, int cb) {           // [32][1024B] x bf16 hi
    return 98304 + row * 1024 + (cb ^ ((row & 7) << 4));
}
__device__ __forceinline__ int adr_xl(int row, int cb) {          // [32][1024B] x bf16 lo
    return 131072 + row * 1024 + (cb ^ ((row & 7) << 4));
}
__device__ __forceinline__ int adr_v(int e, int jb) {             // [512][64B] V natural
    int a = e * 64 + jb;
    return 65536 + (a ^ ((e & 7) << 4));
}

// ---------------- weight fp32 -> bf16 convert (runs once per call) ----------------
__global__ __launch_bounds__(256) void wconvert(const float* __restrict__ wq,
                                                const float* __restrict__ wo,
                                                unsigned short* __restrict__ dst) {
    int i = blockIdx.x * 256 + threadIdx.x;       // float4 index, 262144 total
    const float* src;
    int off;
    if (i < 196608) { src = wq; off = i * 4; }
    else            { src = wo; off = (i - 196608) * 4; }
    float4 v = *(const float4*)(src + off);
    unsigned int lo = f2b(v.x) | ((unsigned int)f2b(v.y) << 16);
    unsigned int hi = f2b(v.z) | ((unsigned int)f2b(v.w) << 16);
    *(uint2*)(dst + (size_t)i * 4) = make_uint2(lo, hi);
}

// ---------------- main fused kernel ----------------
__global__ __launch_bounds__(512, 1)
void axial3d_mfma(const float* __restrict__ x,
                  const float* __restrict__ bq,
                  const float* __restrict__ bo,
                  const unsigned short* __restrict__ wq,   // bf16 [1536][512]
                  const unsigned short* __restrict__ wo,   // bf16 [512][512]
                  float* __restrict__ out) {
    __shared__ char lds[163840];

    const int bid  = blockIdx.x;
    const int work = (bid & 7) * 256 + (bid >> 3);   // XCD-contiguous (b,h) rows
    const int b    = work >> 10;
    const int h    = (work >> 5) & 31;
    const int w    = work & 31;

    const float* xb = x   + ((size_t)b * 16777216u) + h * 32 + w;
    float*       ob = out + ((size_t)b * 16777216u) + h * 32 + w;

    const int tid  = threadIdx.x;
    const int wv   = tid >> 6;
    const int lane = tid & 63;
    const int g    = lane >> 4;     // k-group 0..3
    const int q    = lane & 15;     // within-tile row/col

    // ---------- phase 1: stage x -> xbf[d][c] (+ low-order bf16 for residual) ----------
    {
        const int d  = tid & 31;
        const int c0 = tid >> 5;    // 0..15
        #pragma unroll
        for (int it = 0; it < 32; ++it) {
            int c = c0 + it * 16;
            float xv = xb[c * 32768 + d * 1024];
            unsigned short hi = f2b(xv);
            unsigned short lo = f2b(xv - b2f(hi));
            *(unsigned short*)(lds + adr_x(d, c * 2))  = hi;
            *(unsigned short*)(lds + adr_xl(d, c * 2)) = lo;
        }
    }
    __syncthreads();

    // ---------- phase 2: QKV GEMM (M=1536, N=32, K=512) ----------
    // wave wv owns M-tiles [wv*12, wv*12+12); Q/K stored transposed, V natural
    for (int tp = 0; tp < 3; ++tp) {
        const int mt0 = wv * 12 + tp * 4;
        f32x4 acc[4][2];
        #pragma unroll
        for (int t = 0; t < 4; ++t) { acc[t][0] = (f32x4)0.f; acc[t][1] = (f32x4)0.f; }
        #pragma unroll
        for (int kk = 0; kk < 16; ++kk) {
            bf16x8 bfr[2];
            #pragma unroll
            for (int nt = 0; nt < 2; ++nt)
                bfr[nt] = *(const bf16x8*)(lds + adr_x(nt * 16 + q, kk * 64 + g * 16));
            #pragma unroll
            for (int t = 0; t < 4; ++t) {
                const int o = (mt0 + t) * 16 + q;
                bf16x8 a = *(const bf16x8*)((const char*)wq + o * 1024 + kk * 64 + g * 16);
                acc[t][0] = mfma16(a, bfr[0], acc[t][0]);
                acc[t][1] = mfma16(a, bfr[1], acc[t][1]);
            }
        }
        #pragma unroll
        for (int t = 0; t < 4; ++t) {
            const int mt    = mt0 + t;
            const int obase = mt * 16 + 4 * g;     // rows obase..obase+3
            float bias[4];
            #pragma unroll
            for (int r = 0; r < 4; ++r) bias[r] = bq[obase + r];
            if (mt < 64) {
                // Q (o<512) / K (512<=o<1024): transposed store, colbyte = o*2
                #pragma unroll
                for (int nt = 0; nt < 2; ++nt) {
                    const int d = nt * 16 + q;
                    unsigned int lo = f2b(acc[t][nt][0] + bias[0]) |
                                      ((unsigned int)f2b(acc[t][nt][1] + bias[1]) << 16);
                    unsigned int hi = f2b(acc[t][nt][2] + bias[2]) |
                                      ((unsigned int)f2b(acc[t][nt][3] + bias[3]) << 16);
                    *(uint2*)(lds + adr_qk(d, obase * 2)) = make_uint2(lo, hi);
                }
            } else {
                // V: natural [e][j]
                #pragma unroll
                for (int nt = 0; nt < 2; ++nt) {
                    const int d = nt * 16 + q;
                    #pragma unroll
                    for (int r = 0; r < 4; ++r) {
                        const int e = obase + r - 1024;
                        *(unsigned short*)(lds + adr_v(e, d * 2)) =
                            f2b(acc[t][nt][r] + bias[r]);
                    }
                }
            }
        }
    }
    __syncthreads();

    // ---------- phase 3: attention, head n = wv ----------
    {
        const int n = wv;
        f32x4 s[2][2];
        s[0][0] = (f32x4)0.f; s[0][1] = (f32x4)0.f;
        s[1][0] = (f32x4)0.f; s[1][1] = (f32x4)0.f;
        #pragma unroll
        for (int kk = 0; kk < 2; ++kk) {
            bf16x8 a0 = *(const bf16x8*)(lds + adr_qk(q,      n * 128 + kk * 64 + g * 16));
            bf16x8 a1 = *(const bf16x8*)(lds + adr_qk(16 + q, n * 128 + kk * 64 + g * 16));
            bf16x8 b0 = *(const bf16x8*)(lds + adr_qk(q,      1024 + n * 128 + kk * 64 + g * 16));
            bf16x8 b1 = *(const bf16x8*)(lds + adr_qk(16 + q, 1024 + n * 128 + kk * 64 + g * 16));
            s[0][0] = mfma16(a0, b0, s[0][0]);
            s[0][1] = mfma16(a0, b1, s[0][1]);
            s[1][0] = mfma16(a1, b0, s[1][0]);
            s[1][1] = mfma16(a1, b1, s[1][1]);
        }
        // softmax over j; row i = it*16 + 4g + r lives in the 16 lanes of group g
        float pv[2][2][4];
        #pragma unroll
        for (int it = 0; it < 2; ++it) {
            #pragma unroll
            for (int r = 0; r < 4; ++r) {
                float s0 = s[it][0][r] * 0.125f;
                float s1 = s[it][1][r] * 0.125f;
                float m = fmaxf(s0, s1);
                m = fmaxf(m, __shfl_xor(m, 1));
                m = fmaxf(m, __shfl_xor(m, 2));
                m = fmaxf(m, __shfl_xor(m, 4));
                m = fmaxf(m, __shfl_xor(m, 8));
                float p0 = __expf(s0 - m);
                float p1 = __expf(s1 - m);
                float ss = p0 + p1;
                ss += __shfl_xor(ss, 1);
                ss += __shfl_xor(ss, 2);
                ss += __shfl_xor(ss, 4);
                ss += __shfl_xor(ss, 8);
                float inv = 1.0f / ss;
                pv[it][0][r] = p0 * inv;
                pv[it][1][r] = p1 * inv;
            }
        }
        // store P (bf16) into dead Q slot: [i][j] at colbyte n*128 + j*2
        #pragma unroll
        for (int it = 0; it < 2; ++it)
            #pragma unroll
            for (int jt = 0; jt < 2; ++jt)
                #pragma unroll
                for (int r = 0; r < 4; ++r) {
                    const int i = it * 16 + 4 * g + r;
                    *(unsigned short*)(lds + adr_qk(i, n * 128 + (jt * 16 + q) * 2)) =
                        f2b(pv[it][jt][r]);
                }
        asm volatile("s_waitcnt lgkmcnt(0)" ::: "memory");

        // PV: out[i][e] = sum_j P[i][j] V[e][j]; write aoT into dead K slot
        bf16x8 pa0 = *(const bf16x8*)(lds + adr_qk(q,      n * 128 + g * 16));
        bf16x8 pa1 = *(const bf16x8*)(lds + adr_qk(16 + q, n * 128 + g * 16));
        #pragma unroll
        for (int et = 0; et < 4; ++et) {
            const int e = n * 64 + et * 16 + q;
            bf16x8 vb = *(const bf16x8*)(lds + adr_v(e, g * 16));
            f32x4 o0 = mfma16(pa0, vb, (f32x4)0.f);
            f32x4 o1 = mfma16(pa1, vb, (f32x4)0.f);
            const int cb = 1024 + n * 128 + (et * 16 + q) * 2;
            #pragma unroll
            for (int r = 0; r < 4; ++r) {
                *(unsigned short*)(lds + adr_qk(4 * g + r, cb))      = f2b(o0[r]);
                *(unsigned short*)(lds + adr_qk(16 + 4 * g + r, cb)) = f2b(o1[r]);
            }
        }
    }
    __syncthreads();

    // ---------- phase 4: out projection + bias + residual ----------
    for (int p4 = 0; p4 < 4; ++p4) {
        const int mt = wv * 4 + p4;
        f32x4 acc[2];
        acc[0] = (f32x4)0.f; acc[1] = (f32x4)0.f;
        #pragma unroll
        for (int kk = 0; kk < 16; ++kk) {
            bf16x8 b0 = *(const bf16x8*)(lds + adr_qk(q,      1024 + kk * 64 + g * 16));
            bf16x8 b1 = *(const bf16x8*)(lds + adr_qk(16 + q, 1024 + kk * 64 + g * 16));
            bf16x8 a  = *(const bf16x8*)((const char*)wo + (mt * 16 + q) * 1024 + kk * 64 + g * 16);
            acc[0] = mfma16(a, b0, acc[0]);
            acc[1] = mfma16(a, b1, acc[1]);
        }
        const int obase = mt * 16 + 4 * g;
        float bias[4];
        #pragma unroll
        for (int r = 0; r < 4; ++r) bias[r] = bo[obase + r];
        #pragma unroll
        for (int nt = 0; nt < 2; ++nt) {
            const int d = nt * 16 + q;
            uint2 xh = *(const uint2*)(lds + adr_x(d, obase * 2));
            uint2 xl = *(const uint2*)(lds + adr_xl(d, obase * 2));
            float res[4];
            res[0] = b2f(xh.x & 0xffffu) + b2f(xl.x & 0xffffu);
            res[1] = b2f(xh.x >> 16)     + b2f(xl.x >> 16);
            res[2] = b2f(xh.y & 0xffffu) + b2f(xl.y & 0xffffu);
            res[3] = b2f(xh.y >> 16)     + b2f(xl.y >> 16);
            #pragma unroll
            for (int r = 0; r < 4; ++r) {
                ob[(obase + r) * 32768 + d * 1024] = acc[nt][r] + bias[r] + res[r];
            }
        }
    }
}

extern "C" void kernel_launch(void* const* d_in, const int* in_sizes, int n_in,
                              void* d_out, int out_size, void* d_ws, size_t ws_size,
                              hipStream_t stream) {
    const float* x     = (const float*)d_in[0];
    const float* w_qkv = (const float*)d_in[1];
    const float* b_qkv = (const float*)d_in[2];
    const float* w_out = (const float*)d_in[3];
    const float* b_out = (const float*)d_in[4];
    float* out = (float*)d_out;

    unsigned short* wbf = (unsigned short*)d_ws;          // [0,786432) wqkv, [786432,1048576) wout
    wconvert<<<dim3(1024), dim3(256), 0, stream>>>(w_qkv, w_out, wbf);
    axial3d_mfma<<<dim3(2048), dim3(512), 0, stream>>>(x, b_qkv, b_out,
                                                       wbf, wbf + 786432, out);
}

// Round 3
// 286.265 us; speedup vs baseline: 14.1461x; 3.0393x over previous
//
#include <hip/hip_runtime.h>

// AxialAttention3D — round 3: 4-kernel pipeline (wconvert, xtrans, fused QKV+attn, out-proj)
// B=2, C=512, D=32, H=32, W=32, heads=8, head_dim=64
// Fallback to round-2 fused kernel if ws_size < 130MB.

typedef __bf16 bf16x8 __attribute__((ext_vector_type(8)));
typedef float  f32x4  __attribute__((ext_vector_type(4)));

__device__ __forceinline__ float b2f(unsigned int u) {
    union { float f; unsigned int i; } x; x.i = u << 16; return x.f;
}
__device__ __forceinline__ unsigned short f2b(float f) {
    union { float f; unsigned int i; } x; x.f = f;
    unsigned int r = x.i + 0x7FFFu + ((x.i >> 16) & 1u);
    return (unsigned short)(r >> 16);
}
__device__ __forceinline__ f32x4 mfma16(bf16x8 a, bf16x8 b, f32x4 c) {
    return __builtin_amdgcn_mfma_f32_16x16x32_bf16(a, b, c, 0, 0, 0);
}
__device__ __forceinline__ void gload16(const void* g, void* l) {
    __builtin_amdgcn_global_load_lds((const unsigned int*)g, (unsigned int*)l, 16, 0, 0);
}

// ======================= weight fp32 -> bf16 =======================
__global__ __launch_bounds__(256) void wconvert(const float* __restrict__ wq,
                                                const float* __restrict__ wo,
                                                unsigned short* __restrict__ dst) {
    int i = blockIdx.x * 256 + threadIdx.x;       // float4 index, 262144 total
    const float* src;
    int off;
    if (i < 196608) { src = wq; off = i * 4; }
    else            { src = wo; off = (i - 196608) * 4; }
    float4 v = *(const float4*)(src + off);
    unsigned int lo = f2b(v.x) | ((unsigned int)f2b(v.y) << 16);
    unsigned int hi = f2b(v.z) | ((unsigned int)f2b(v.w) << 16);
    *(uint2*)(dst + (size_t)i * 4) = make_uint2(lo, hi);
}

// ======================= x [c][s] fp32 -> xT [s][c] bf16 =======================
__global__ __launch_bounds__(256) void xtrans(const float* __restrict__ x,
                                              unsigned short* __restrict__ xT) {
    __shared__ __align__(16) char tile[32768];    // [256 s][64 c] bf16, XOR-swizzled
    const int bid = blockIdx.x;
    const int c0  = (bid & 7) * 64;
    const int s0  = (bid >> 3) * 256;             // 256-aligned: never straddles batch
    const int b   = s0 >> 15;
    const int sp0 = s0 & 32767;

    const int u  = threadIdx.x & 31;              // c-pair index
    const int so = threadIdx.x >> 5;              // s-group of 32
    const float* p0 = x + (size_t)b * 16777216 + (size_t)(c0 + 2 * u) * 32768 + sp0 + so * 32;
    const float* p1 = p0 + 32768;
    #pragma unroll
    for (int k = 0; k < 8; ++k) {
        float4 a = *(const float4*)(p0 + 4 * k);
        float4 c = *(const float4*)(p1 + 4 * k);
        const float* af = (const float*)&a;
        const float* cf = (const float*)&c;
        #pragma unroll
        for (int i = 0; i < 4; ++i) {
            int s = so * 32 + 4 * k + i;
            unsigned int pk = f2b(af[i]) | ((unsigned int)f2b(cf[i]) << 16);
            *(unsigned int*)(tile + s * 128 + ((((u >> 2) ^ (s & 7)) << 4) | ((u & 3) << 2))) = pk;
        }
    }
    __syncthreads();
    const int sl = threadIdx.x;                   // row 0..255
    unsigned short* dst = xT + (size_t)(s0 + sl) * 512 + c0;
    #pragma unroll
    for (int h = 0; h < 8; ++h) {
        uint4 v = *(const uint4*)(tile + sl * 128 + ((h ^ (sl & 7)) << 4));
        *(uint4*)(dst + h * 8) = v;
    }
}

// ======================= fused QKV-GEMM + attention =======================
// block = (head n, group of 4 w). GEMM: M=192 (Q|K|V rows of head), N=128 (4w x 32d), K=512.
__global__ __launch_bounds__(256, 2)
void axial_ab(const unsigned short* __restrict__ xT,   // [65536][512] bf16
              const unsigned short* __restrict__ wq,   // [1536][512] bf16
              const float* __restrict__ bq,
              unsigned short* __restrict__ ao)         // [65536][512] bf16
{
    __shared__ __align__(16) char lds[81920];
    // staging: A [0,49152) = 2 x [192][128B]; B [49152,81920) = 2 x [128][128B]
    // attn (after GEMM): QT [0,16384): [32 d][512B]; KT [16384,32768); VT [32768,49152): [64 c][256B]; P [49152,57344): 4 x [32][64B]

    const int bid = blockIdx.x;
    const int vid = (bid & 7) * 512 + (bid >> 3);
    const int n   = vid & 7;
    const int tg  = vid >> 3;                     // 0..511
    const int b   = tg >> 8;
    const int h   = (tg >> 3) & 31;
    const int w0  = (tg & 7) * 4;
    const int sbase = b * 32768 + h * 32 + w0;    // + d*1024 + t

    const int tid = threadIdx.x;
    const int wv  = tid >> 6;
    const int l   = tid & 63;
    const int q   = l & 15;
    const int g   = l >> 4;
    const int wm  = wv >> 1;
    const int wn  = wv & 1;

    auto stage = [&](int kk, int buf) {
        // A: weights, 6 wave-loads (rows il*8..il*8+7, swizzled source)
        #pragma unroll
        for (int i = 0; i < 6; ++i) {
            const int il  = wv * 6 + i;
            const int row = il * 8 + (l >> 3);
            const int R   = n * 64 + (row & 63) + ((row >> 6) << 9);
            const unsigned short* src = wq + R * 512 + kk * 64 + (((l & 7) ^ (row & 7)) << 3);
            gload16(src, lds + buf * 24576 + il * 1024);
        }
        // B: xT, 4 wave-loads
        #pragma unroll
        for (int i = 0; i < 4; ++i) {
            const int il  = wv * 4 + i;
            const int row = il * 8 + (l >> 3);        // j = 0..127
            const int d   = row & 31;
            const int wr  = row >> 5;
            const int s   = sbase + d * 1024 + wr;
            const unsigned short* src = xT + (size_t)s * 512 + kk * 64 + (((l & 7) ^ (row & 7)) << 3);
            gload16(src, lds + 49152 + buf * 16384 + il * 1024);
        }
    };

    f32x4 acc[6][4];
    #pragma unroll
    for (int mf = 0; mf < 6; ++mf)
        #pragma unroll
        for (int nf = 0; nf < 4; ++nf) acc[mf][nf] = (f32x4)0.f;

    stage(0, 0);
    __syncthreads();
    int cur = 0;
    for (int kk = 0; kk < 8; ++kk) {
        if (kk < 7) stage(kk + 1, cur ^ 1);
        #pragma unroll
        for (int kh = 0; kh < 2; ++kh) {
            bf16x8 af[6], bfr[4];
            #pragma unroll
            for (int mf = 0; mf < 6; ++mf) {
                const int row = wm * 96 + mf * 16 + q;
                af[mf] = *(const bf16x8*)(lds + cur * 24576 + row * 128 +
                                          (((kh * 4 + g) ^ (row & 7)) << 4));
            }
            #pragma unroll
            for (int nf = 0; nf < 4; ++nf) {
                const int row = wn * 64 + nf * 16 + q;
                bfr[nf] = *(const bf16x8*)(lds + 49152 + cur * 16384 + row * 128 +
                                           (((kh * 4 + g) ^ (row & 7)) << 4));
            }
            #pragma unroll
            for (int mf = 0; mf < 6; ++mf)
                #pragma unroll
                for (int nf = 0; nf < 4; ++nf)
                    acc[mf][nf] = mfma16(af[mf], bfr[nf], acc[mf][nf]);
        }
        __syncthreads();
        cur ^= 1;
    }

    // ---- epilogue: scatter C (+bias) into attention layouts ----
    #pragma unroll
    for (int mf = 0; mf < 6; ++mf) {
        const int m0 = wm * 96 + mf * 16 + 4 * g;
        const int R0 = n * 64 + (m0 & 63) + ((m0 >> 6) << 9);
        float bias[4];
        #pragma unroll
        for (int r = 0; r < 4; ++r) bias[r] = bq[R0 + r];
        #pragma unroll
        for (int nf = 0; nf < 4; ++nf) {
            const int j = wn * 64 + nf * 16 + q;
            const int t = j >> 5;
            const int d = j & 31;
            f32x4 v = acc[mf][nf];
            if (m0 < 128) {
                // Q (m0<64) or K: transposed store [d][t*64+c], 4-pack b64
                const int base = (m0 < 64) ? 0 : 16384;
                const int c0 = m0 & 63;
                unsigned int lo = f2b(v[0] + bias[0]) | ((unsigned int)f2b(v[1] + bias[1]) << 16);
                unsigned int hi = f2b(v[2] + bias[2]) | ((unsigned int)f2b(v[3] + bias[3]) << 16);
                const int lin = (t * 64 + c0) * 2;
                *(uint2*)(lds + base + d * 512 + (lin ^ ((d & 7) << 4))) = make_uint2(lo, hi);
            } else {
                // V: [c][t*32+d]
                #pragma unroll
                for (int r = 0; r < 4; ++r) {
                    const int c = m0 - 128 + r;
                    const int lin = (t * 32 + d) * 2;
                    *(unsigned short*)(lds + 32768 + c * 256 + (lin ^ ((c & 7) << 4))) =
                        f2b(v[r] + bias[r]);
                }
            }
        }
    }
    __syncthreads();

    // ---- attention: wave wv handles t = wv ----
    {
        const int t = wv;
        f32x4 sacc[2][2];
        sacc[0][0] = (f32x4)0.f; sacc[0][1] = (f32x4)0.f;
        sacc[1][0] = (f32x4)0.f; sacc[1][1] = (f32x4)0.f;
        #pragma unroll
        for (int kh = 0; kh < 2; ++kh) {
            bf16x8 qa[2], kb[2];
            #pragma unroll
            for (int mt = 0; mt < 2; ++mt) {
                const int i = mt * 16 + q;
                qa[mt] = *(const bf16x8*)(lds + i * 512 + (((t * 8 + kh * 4 + g) ^ (i & 7)) << 4));
            }
            #pragma unroll
            for (int nt = 0; nt < 2; ++nt) {
                const int jj = nt * 16 + q;
                kb[nt] = *(const bf16x8*)(lds + 16384 + jj * 512 +
                                          (((t * 8 + kh * 4 + g) ^ (jj & 7)) << 4));
            }
            #pragma unroll
            for (int mt = 0; mt < 2; ++mt)
                #pragma unroll
                for (int nt = 0; nt < 2; ++nt)
                    sacc[mt][nt] = mfma16(qa[mt], kb[nt], sacc[mt][nt]);
        }
        // softmax over j (32), rows i = mt*16 + 4g + reg
        #pragma unroll
        for (int mt = 0; mt < 2; ++mt) {
            #pragma unroll
            for (int reg = 0; reg < 4; ++reg) {
                float s0 = sacc[mt][0][reg] * 0.125f;
                float s1 = sacc[mt][1][reg] * 0.125f;
                float m = fmaxf(s0, s1);
                m = fmaxf(m, __shfl_xor(m, 1));
                m = fmaxf(m, __shfl_xor(m, 2));
                m = fmaxf(m, __shfl_xor(m, 4));
                m = fmaxf(m, __shfl_xor(m, 8));
                float p0 = __expf(s0 - m);
                float p1 = __expf(s1 - m);
                float ss = p0 + p1;
                ss += __shfl_xor(ss, 1);
                ss += __shfl_xor(ss, 2);
                ss += __shfl_xor(ss, 4);
                ss += __shfl_xor(ss, 8);
                float inv = 1.0f / ss;
                const int i = mt * 16 + g * 4 + reg;
                const int j0 = q;
                const int j1 = 16 + q;
                *(unsigned short*)(lds + 49152 + t * 2048 + i * 64 + ((j0 * 2) ^ ((i & 3) << 4))) =
                    f2b(p0 * inv);
                *(unsigned short*)(lds + 49152 + t * 2048 + i * 64 + ((j1 * 2) ^ ((i & 3) << 4))) =
                    f2b(p1 * inv);
            }
        }
        asm volatile("s_waitcnt lgkmcnt(0)" ::: "memory");
        __builtin_amdgcn_sched_barrier(0);

        // PV: out(i, c) = sum_j P[i][j] * V[c][j]
        bf16x8 pa[2];
        #pragma unroll
        for (int mt = 0; mt < 2; ++mt) {
            const int i = mt * 16 + q;
            pa[mt] = *(const bf16x8*)(lds + 49152 + t * 2048 + i * 64 + ((g ^ (i & 3)) << 4));
        }
        f32x4 oacc[2][4];
        #pragma unroll
        for (int ct = 0; ct < 4; ++ct) {
            const int c = ct * 16 + q;
            bf16x8 vb = *(const bf16x8*)(lds + 32768 + c * 256 + (((t * 4 + g) ^ (c & 7)) << 4));
            #pragma unroll
            for (int mt = 0; mt < 2; ++mt)
                oacc[mt][ct] = mfma16(pa[mt], vb, (f32x4)0.f);
        }
        // write ao[s][c] bf16
        #pragma unroll
        for (int mt = 0; mt < 2; ++mt)
            #pragma unroll
            for (int ct = 0; ct < 4; ++ct)
                #pragma unroll
                for (int r = 0; r < 4; ++r) {
                    const int d = mt * 16 + g * 4 + r;
                    const int s = sbase + d * 1024 + t;
                    const int cg = n * 64 + ct * 16 + q;
                    ao[(size_t)s * 512 + cg] = f2b(oacc[mt][ct][r]);
                }
    }
}

// ======================= out-projection GEMM + bias + residual =======================
__global__ __launch_bounds__(256, 2)
void axial_out(const unsigned short* __restrict__ ao,  // [65536][512] bf16
               const unsigned short* __restrict__ wo,  // [512][512] bf16
               const float* __restrict__ bo,
               const float* __restrict__ x,
               float* __restrict__ out)
{
    __shared__ __align__(16) char lds[65536];
    // A [0,32768) = 2 x [128][128B] (wo rows); B [32768,65536) = 2 x [128][128B] (ao rows)

    const int bid = blockIdx.x;
    const int vid = (bid & 7) * 256 + (bid >> 3);
    const int mt_ = vid & 3;
    const int nt_ = vid >> 2;                     // 0..511
    const int m_base = mt_ * 128;
    const int s_base = nt_ * 128;
    const int bb  = s_base >> 15;
    const int spl = s_base & 32767;
    const float* xblk = x + (size_t)bb * 16777216 + spl;
    float* oblk = out + (size_t)bb * 16777216 + spl;

    const int tid = threadIdx.x;
    const int wv  = tid >> 6;
    const int l   = tid & 63;
    const int q   = l & 15;
    const int g   = l >> 4;
    const int wm  = wv >> 1;
    const int wn  = wv & 1;

    auto stage = [&](int kk, int buf) {
        #pragma unroll
        for (int i = 0; i < 4; ++i) {
            const int il  = wv * 4 + i;
            const int row = il * 8 + (l >> 3);
            const unsigned short* srcA = wo + (m_base + row) * 512 + kk * 64 +
                                         (((l & 7) ^ (row & 7)) << 3);
            gload16(srcA, lds + buf * 16384 + il * 1024);
            const unsigned short* srcB = ao + (size_t)(s_base + row) * 512 + kk * 64 +
                                         (((l & 7) ^ (row & 7)) << 3);
            gload16(srcB, lds + 32768 + buf * 16384 + il * 1024);
        }
    };

    f32x4 acc[4][4];
    #pragma unroll
    for (int mf = 0; mf < 4; ++mf)
        #pragma unroll
        for (int nf = 0; nf < 4; ++nf) acc[mf][nf] = (f32x4)0.f;

    stage(0, 0);
    __syncthreads();
    int cur = 0;
    for (int kk = 0; kk < 8; ++kk) {
        if (kk < 7) stage(kk + 1, cur ^ 1);
        #pragma unroll
        for (int kh = 0; kh < 2; ++kh) {
            bf16x8 af[4], bfr[4];
            #pragma unroll
            for (int mf = 0; mf < 4; ++mf) {
                const int row = wm * 64 + mf * 16 + q;
                af[mf] = *(const bf16x8*)(lds + cur * 16384 + row * 128 +
                                          (((kh * 4 + g) ^ (row & 7)) << 4));
            }
            #pragma unroll
            for (int nf = 0; nf < 4; ++nf) {
                const int row = wn * 64 + nf * 16 + q;
                bfr[nf] = *(const bf16x8*)(lds + 32768 + cur * 16384 + row * 128 +
                                           (((kh * 4 + g) ^ (row & 7)) << 4));
            }
            #pragma unroll
            for (int mf = 0; mf < 4; ++mf)
                #pragma unroll
                for (int nf = 0; nf < 4; ++nf)
                    acc[mf][nf] = mfma16(af[mf], bfr[nf], acc[mf][nf]);
        }
        __syncthreads();
        cur ^= 1;
    }

    // epilogue: + bias + residual, coalesced fp32 stores
    #pragma unroll
    for (int mf = 0; mf < 4; ++mf) {
        const int m0 = wm * 64 + mf * 16 + 4 * g;
        #pragma unroll
        for (int r = 0; r < 4; ++r) {
            const int co = m_base + m0 + r;
            const float bias = bo[co];
            #pragma unroll
            for (int nf = 0; nf < 4; ++nf) {
                const int sl = wn * 64 + nf * 16 + q;
                float val = acc[mf][nf][r] + bias + xblk[(size_t)co * 32768 + sl];
                oblk[(size_t)co * 32768 + sl] = val;
            }
        }
    }
}

// ======================= round-2 fallback (fully fused) =======================
__device__ __forceinline__ int adr_qk(int row, int cb) { return row * 2048 + (cb ^ ((row & 7) << 4)); }
__device__ __forceinline__ int adr_x (int row, int cb) { return 98304 + row * 1024 + (cb ^ ((row & 7) << 4)); }
__device__ __forceinline__ int adr_xl(int row, int cb) { return 131072 + row * 1024 + (cb ^ ((row & 7) << 4)); }
__device__ __forceinline__ int adr_v (int e, int jb)   { int a = e * 64 + jb; return 65536 + (a ^ ((e & 7) << 4)); }

__global__ __launch_bounds__(512, 1)
void axial3d_mfma(const float* __restrict__ x,
                  const float* __restrict__ bq,
                  const float* __restrict__ bo,
                  const unsigned short* __restrict__ wq,
                  const unsigned short* __restrict__ wo,
                  float* __restrict__ out) {
    __shared__ char lds[163840];
    const int bid  = blockIdx.x;
    const int work = (bid & 7) * 256 + (bid >> 3);
    const int b    = work >> 10;
    const int h    = (work >> 5) & 31;
    const int w    = work & 31;
    const float* xb = x   + ((size_t)b * 16777216u) + h * 32 + w;
    float*       ob = out + ((size_t)b * 16777216u) + h * 32 + w;
    const int tid  = threadIdx.x;
    const int wv   = tid >> 6;
    const int lane = tid & 63;
    const int g    = lane >> 4;
    const int q    = lane & 15;
    {
        const int d  = tid & 31;
        const int c0 = tid >> 5;
        #pragma unroll
        for (int it = 0; it < 32; ++it) {
            int c = c0 + it * 16;
            float xv = xb[c * 32768 + d * 1024];
            unsigned short hi = f2b(xv);
            unsigned short lo = f2b(xv - b2f(hi));
            *(unsigned short*)(lds + adr_x(d, c * 2))  = hi;
            *(unsigned short*)(lds + adr_xl(d, c * 2)) = lo;
        }
    }
    __syncthreads();
    for (int tp = 0; tp < 3; ++tp) {
        const int mt0 = wv * 12 + tp * 4;
        f32x4 acc[4][2];
        #pragma unroll
        for (int t = 0; t < 4; ++t) { acc[t][0] = (f32x4)0.f; acc[t][1] = (f32x4)0.f; }
        #pragma unroll
        for (int kk = 0; kk < 16; ++kk) {
            bf16x8 bfr[2];
            #pragma unroll
            for (int nt = 0; nt < 2; ++nt)
                bfr[nt] = *(const bf16x8*)(lds + adr_x(nt * 16 + q, kk * 64 + g * 16));
            #pragma unroll
            for (int t = 0; t < 4; ++t) {
                const int o = (mt0 + t) * 16 + q;
                bf16x8 a = *(const bf16x8*)((const char*)wq + o * 1024 + kk * 64 + g * 16);
                acc[t][0] = mfma16(a, bfr[0], acc[t][0]);
                acc[t][1] = mfma16(a, bfr[1], acc[t][1]);
            }
        }
        #pragma unroll
        for (int t = 0; t < 4; ++t) {
            const int mt    = mt0 + t;
            const int obase = mt * 16 + 4 * g;
            float bias[4];
            #pragma unroll
            for (int r = 0; r < 4; ++r) bias[r] = bq[obase + r];
            if (mt < 64) {
                #pragma unroll
                for (int nt = 0; nt < 2; ++nt) {
                    const int d = nt * 16 + q;
                    unsigned int lo = f2b(acc[t][nt][0] + bias[0]) |
                                      ((unsigned int)f2b(acc[t][nt][1] + bias[1]) << 16);
                    unsigned int hi = f2b(acc[t][nt][2] + bias[2]) |
                                      ((unsigned int)f2b(acc[t][nt][3] + bias[3]) << 16);
                    *(uint2*)(lds + adr_qk(d, obase * 2)) = make_uint2(lo, hi);
                }
            } else {
                #pragma unroll
                for (int nt = 0; nt < 2; ++nt) {
                    const int d = nt * 16 + q;
                    #pragma unroll
                    for (int r = 0; r < 4; ++r) {
                        const int e = obase + r - 1024;
                        *(unsigned short*)(lds + adr_v(e, d * 2)) = f2b(acc[t][nt][r] + bias[r]);
                    }
                }
            }
        }
    }
    __syncthreads();
    {
        const int n = wv;
        f32x4 s[2][2];
        s[0][0] = (f32x4)0.f; s[0][1] = (f32x4)0.f;
        s[1][0] = (f32x4)0.f; s[1][1] = (f32x4)0.f;
        #pragma unroll
        for (int kk = 0; kk < 2; ++kk) {
            bf16x8 a0 = *(const bf16x8*)(lds + adr_qk(q,      n * 128 + kk * 64 + g * 16));
            bf16x8 a1 = *(const bf16x8*)(lds + adr_qk(16 + q, n * 128 + kk * 64 + g * 16));
            bf16x8 b0 = *(const bf16x8*)(lds + adr_qk(q,      1024 + n * 128 + kk * 64 + g * 16));
            bf16x8 b1 = *(const bf16x8*)(lds + adr_qk(16 + q, 1024 + n * 128 + kk * 64 + g * 16));
            s[0][0] = mfma16(a0, b0, s[0][0]);
            s[0][1] = mfma16(a0, b1, s[0][1]);
            s[1][0] = mfma16(a1, b0, s[1][0]);
            s[1][1] = mfma16(a1, b1, s[1][1]);
        }
        float pv[2][2][4];
        #pragma unroll
        for (int it = 0; it < 2; ++it) {
            #pragma unroll
            for (int r = 0; r < 4; ++r) {
                float s0 = s[it][0][r] * 0.125f;
                float s1 = s[it][1][r] * 0.125f;
                float m = fmaxf(s0, s1);
                m = fmaxf(m, __shfl_xor(m, 1));
                m = fmaxf(m, __shfl_xor(m, 2));
                m = fmaxf(m, __shfl_xor(m, 4));
                m = fmaxf(m, __shfl_xor(m, 8));
                float p0 = __expf(s0 - m);
                float p1 = __expf(s1 - m);
                float ss = p0 + p1;
                ss += __shfl_xor(ss, 1);
                ss += __shfl_xor(ss, 2);
                ss += __shfl_xor(ss, 4);
                ss += __shfl_xor(ss, 8);
                float inv = 1.0f / ss;
                pv[it][0][r] = p0 * inv;
                pv[it][1][r] = p1 * inv;
            }
        }
        #pragma unroll
        for (int it = 0; it < 2; ++it)
            #pragma unroll
            for (int jt = 0; jt < 2; ++jt)
                #pragma unroll
                for (int r = 0; r < 4; ++r) {
                    const int i = it * 16 + 4 * g + r;
                    *(unsigned short*)(lds + adr_qk(i, n * 128 + (jt * 16 + q) * 2)) =
                        f2b(pv[it][jt][r]);
                }
        asm volatile("s_waitcnt lgkmcnt(0)" ::: "memory");
        __builtin_amdgcn_sched_barrier(0);
        bf16x8 pa0 = *(const bf16x8*)(lds + adr_qk(q,      n * 128 + g * 16));
        bf16x8 pa1 = *(const bf16x8*)(lds + adr_qk(16 + q, n * 128 + g * 16));
        #pragma unroll
        for (int et = 0; et < 4; ++et) {
            const int e = n * 64 + et * 16 + q;
            bf16x8 vb = *(const bf16x8*)(lds + adr_v(e, g * 16));
            f32x4 o0 = mfma16(pa0, vb, (f32x4)0.f);
            f32x4 o1 = mfma16(pa1, vb, (f32x4)0.f);
            const int cb = 1024 + n * 128 + (et * 16 + q) * 2;
            #pragma unroll
            for (int r = 0; r < 4; ++r) {
                *(unsigned short*)(lds + adr_qk(4 * g + r, cb))      = f2b(o0[r]);
                *(unsigned short*)(lds + adr_qk(16 + 4 * g + r, cb)) = f2b(o1[r]);
            }
        }
    }
    __syncthreads();
    for (int p4 = 0; p4 < 4; ++p4) {
        const int mt = wv * 4 + p4;
        f32x4 acc[2];
        acc[0] = (f32x4)0.f; acc[1] = (f32x4)0.f;
        #pragma unroll
        for (int kk = 0; kk < 16; ++kk) {
            bf16x8 b0 = *(const bf16x8*)(lds + adr_qk(q,      1024 + kk * 64 + g * 16));
            bf16x8 b1 = *(const bf16x8*)(lds + adr_qk(16 + q, 1024 + kk * 64 + g * 16));
            bf16x8 a  = *(const bf16x8*)((const char*)wo + (mt * 16 + q) * 1024 + kk * 64 + g * 16);
            acc[0] = mfma16(a, b0, acc[0]);
            acc[1] = mfma16(a, b1, acc[1]);
        }
        const int obase = mt * 16 + 4 * g;
        float bias[4];
        #pragma unroll
        for (int r = 0; r < 4; ++r) bias[r] = bo[obase + r];
        #pragma unroll
        for (int nt = 0; nt < 2; ++nt) {
            const int d = nt * 16 + q;
            uint2 xh = *(const uint2*)(lds + adr_x(d, obase * 2));
            uint2 xl = *(const uint2*)(lds + adr_xl(d, obase * 2));
            float res[4];
            res[0] = b2f(xh.x & 0xffffu) + b2f(xl.x & 0xffffu);
            res[1] = b2f(xh.x >> 16)     + b2f(xl.x >> 16);
            res[2] = b2f(xh.y & 0xffffu) + b2f(xl.y & 0xffffu);
            res[3] = b2f(xh.y >> 16)     + b2f(xl.y >> 16);
            #pragma unroll
            for (int r = 0; r < 4; ++r)
                ob[(obase + r) * 32768 + d * 1024] = acc[nt][r] + bias[r] + res[r];
        }
    }
}

// ======================= launch =======================
extern "C" void kernel_launch(void* const* d_in, const int* in_sizes, int n_in,
                              void* d_out, int out_size, void* d_ws, size_t ws_size,
                              hipStream_t stream) {
    const float* x     = (const float*)d_in[0];
    const float* w_qkv = (const float*)d_in[1];
    const float* b_qkv = (const float*)d_in[2];
    const float* w_out = (const float*)d_in[3];
    const float* b_out = (const float*)d_in[4];
    float* out = (float*)d_out;

    const size_t XT_OFF = 0;                 // 64 MB bf16 [65536][512]
    const size_t AO_OFF = 67108864;          // 64 MB bf16 [65536][512]
    const size_t WQ_OFF = 134217728;         // 1.5 MB
    const size_t NEED   = 136314880;

    if (ws_size >= NEED) {
        unsigned short* xT  = (unsigned short*)((char*)d_ws + XT_OFF);
        unsigned short* ao  = (unsigned short*)((char*)d_ws + AO_OFF);
        unsigned short* wbf = (unsigned short*)((char*)d_ws + WQ_OFF);
        wconvert<<<dim3(1024), dim3(256), 0, stream>>>(w_qkv, w_out, wbf);
        xtrans  <<<dim3(2048), dim3(256), 0, stream>>>(x, xT);
        axial_ab<<<dim3(4096), dim3(256), 0, stream>>>(xT, wbf, b_qkv, ao);
        axial_out<<<dim3(2048), dim3(256), 0, stream>>>(ao, wbf + 786432, b_out, x, out);
    } else {
        unsigned short* wbf = (unsigned short*)d_ws;
        wconvert<<<dim3(1024), dim3(256), 0, stream>>>(w_qkv, w_out, wbf);
        axial3d_mfma<<<dim3(2048), dim3(512), 0, stream>>>(x, b_qkv, b_out,
                                                           wbf, wbf + 786432, out);
    }
}

// Round 4
// 278.442 us; speedup vs baseline: 14.5435x; 1.0281x over previous
//
#include <hip/hip_runtime.h>

// AxialAttention3D — round 4: 32x32 MFMA + cvt_pk + transposed PV + merged xprep
// B=2, C=512, D=32, H=32, W=32, heads=8, head_dim=64

typedef __bf16 bf16x8 __attribute__((ext_vector_type(8)));
typedef float  f32x4  __attribute__((ext_vector_type(4)));
typedef float  f32x16 __attribute__((ext_vector_type(16)));

__device__ __forceinline__ float b2f(unsigned int u) {
    union { float f; unsigned int i; } x; x.i = u << 16; return x.f;
}
__device__ __forceinline__ unsigned short f2b(float f) {
    union { float f; unsigned int i; } x; x.f = f;
    unsigned int r = x.i + 0x7FFFu + ((x.i >> 16) & 1u);
    return (unsigned short)(r >> 16);
}
__device__ __forceinline__ unsigned int cvtpk(float lo, float hi) {
    unsigned int r;
    asm("v_cvt_pk_bf16_f32 %0, %1, %2" : "=v"(r) : "v"(lo), "v"(hi));
    return r;
}
__device__ __forceinline__ f32x4 mfma16(bf16x8 a, bf16x8 b, f32x4 c) {
    return __builtin_amdgcn_mfma_f32_16x16x32_bf16(a, b, c, 0, 0, 0);
}
__device__ __forceinline__ f32x16 mfma32(bf16x8 a, bf16x8 b, f32x16 c) {
    return __builtin_amdgcn_mfma_f32_32x32x16_bf16(a, b, c, 0, 0, 0);
}
__device__ __forceinline__ void gload16(const void* g, void* l) {
    __builtin_amdgcn_global_load_lds((const unsigned int*)g, (unsigned int*)l, 16, 0, 0);
}

// ======================= xprep: x transpose->bf16  +  weight convert =======================
__global__ __launch_bounds__(256) void xprep(const float* __restrict__ x,
                                             const float* __restrict__ wq_f,
                                             const float* __restrict__ wo_f,
                                             unsigned short* __restrict__ xT,
                                             unsigned short* __restrict__ wbf) {
    const int bid = blockIdx.x;
    const int t   = threadIdx.x;
    if (bid >= 2048) {
        // weight fp32 -> bf16: 262144 float4 items over 256 blocks
        int i0 = (bid - 2048) * 1024 + t;
        #pragma unroll
        for (int k = 0; k < 4; ++k) {
            int i = i0 + k * 256;
            const float* src;
            int off;
            if (i < 196608) { src = wq_f; off = i * 4; }
            else            { src = wo_f; off = (i - 196608) * 4; }
            float4 v = *(const float4*)(src + off);
            *(uint2*)(wbf + (size_t)i * 4) = make_uint2(cvtpk(v.x, v.y), cvtpk(v.z, v.w));
        }
        return;
    }
    __shared__ __align__(16) char tile[32768];   // [256 s][64 c] bf16, granule-swizzled
    const int c0 = (bid & 7) * 64;
    const int s0 = (bid >> 3) * 256;             // 256-aligned: never straddles batch
    const int b  = s0 >> 15;
    const int sp = s0 & 32767;

    // read: thread covers c-rows c0+(t&7)*8+j, s-range sp+(t>>3)*8..+7
    const float* px = x + (size_t)b * 16777216 + (size_t)(c0 + (t & 7) * 8) * 32768 + sp + (t >> 3) * 8;
    float va[8][8];
    #pragma unroll
    for (int j = 0; j < 8; ++j) {
        float4 a0 = *(const float4*)(px + (size_t)j * 32768);
        float4 a1 = *(const float4*)(px + (size_t)j * 32768 + 4);
        va[j][0] = a0.x; va[j][1] = a0.y; va[j][2] = a0.z; va[j][3] = a0.w;
        va[j][4] = a1.x; va[j][5] = a1.y; va[j][6] = a1.z; va[j][7] = a1.w;
    }
    #pragma unroll
    for (int k = 0; k < 8; ++k) {
        uint4 o = make_uint4(cvtpk(va[0][k], va[1][k]), cvtpk(va[2][k], va[3][k]),
                             cvtpk(va[4][k], va[5][k]), cvtpk(va[6][k], va[7][k]));
        const int srow = (t >> 3) * 8 + k;       // srow&7 == k
        *(uint4*)(tile + srow * 128 + (((t & 7) ^ k) << 4)) = o;
    }
    __syncthreads();
    unsigned short* dst = xT + (size_t)(s0 + t) * 512 + c0;
    #pragma unroll
    for (int m = 0; m < 8; ++m) {
        uint4 v = *(const uint4*)(tile + t * 128 + ((m ^ (t & 7)) << 4));
        *(uint4*)(dst + m * 8) = v;
    }
}

// ======================= fused QKV-GEMM + attention (32x32 frags) =======================
// block = (head n, group of 4 w). GEMM: M=192, N=128 (4w x 32d), K=512.
__global__ __launch_bounds__(256, 2)
void axial_ab(const unsigned short* __restrict__ xT,   // [65536][512] bf16
              const unsigned short* __restrict__ wq,   // [1536][512] bf16
              const float* __restrict__ bq,
              unsigned short* __restrict__ ao)         // [65536][512] bf16
{
    __shared__ __align__(16) char lds[81920];
    // staging: A [0,49152) = 2 x [192][128B]; B [49152,81920) = 2 x [128][128B]
    // attn:    QT [0,16384) = [4t][32 d][128B c]; KT [16384,32768); VT [32768,49152) = [64 e][256B j];
    //          P [49152,57344) = [4t][32 i][64B j]; bias [57344,58112) = 192 f32
    const int QT0 = 0, KT0 = 16384, VT0 = 32768, P0 = 49152, BIAS0 = 57344;
    float* bias_s = (float*)(lds + BIAS0);

    const int bid = blockIdx.x;
    const int vid = (bid & 7) * 512 + (bid >> 3);
    const int n   = vid & 7;
    const int tg  = vid >> 3;
    const int b   = tg >> 8;
    const int h   = (tg >> 3) & 31;
    const int w0  = (tg & 7) * 4;
    const int sbase = b * 32768 + h * 32 + w0;

    const int tid = threadIdx.x;
    const int wv  = tid >> 6;
    const int l   = tid & 63;
    const int l31 = l & 31;
    const int hh  = l >> 5;
    const int wm  = wv >> 1;
    const int wn  = wv & 1;

    auto stage = [&](int kk, int buf) {
        #pragma unroll
        for (int i = 0; i < 6; ++i) {
            const int il  = wv * 6 + i;
            const int row = il * 8 + (l >> 3);
            const int R   = n * 64 + (row & 63) + ((row >> 6) << 9);
            const unsigned short* src = wq + R * 512 + kk * 64 + (((l & 7) ^ (row & 7)) << 3);
            gload16(src, lds + buf * 24576 + il * 1024);
        }
        #pragma unroll
        for (int i = 0; i < 4; ++i) {
            const int il  = wv * 4 + i;
            const int row = il * 8 + (l >> 3);
            const int d   = row & 31;
            const int wr  = row >> 5;
            const int s   = sbase + d * 1024 + wr;
            const unsigned short* src = xT + (size_t)s * 512 + kk * 64 + (((l & 7) ^ (row & 7)) << 3);
            gload16(src, lds + 49152 + buf * 16384 + il * 1024);
        }
    };

    f32x16 acc[3][2];
    #pragma unroll
    for (int mf = 0; mf < 3; ++mf)
        #pragma unroll
        for (int nf = 0; nf < 2; ++nf) acc[mf][nf] = (f32x16)0.f;

    stage(0, 0);
    __syncthreads();
    int cur = 0;
    for (int kk = 0; kk < 8; ++kk) {
        if (kk < 7) stage(kk + 1, cur ^ 1);
        #pragma unroll
        for (int ks = 0; ks < 4; ++ks) {
            bf16x8 af[3], bfr[2];
            #pragma unroll
            for (int mf = 0; mf < 3; ++mf) {
                const int row = wm * 96 + mf * 32 + l31;
                af[mf] = *(const bf16x8*)(lds + cur * 24576 + row * 128 +
                                          (((ks * 2 + hh) ^ (row & 7)) << 4));
            }
            #pragma unroll
            for (int nf = 0; nf < 2; ++nf) {
                const int row = wn * 64 + nf * 32 + l31;
                bfr[nf] = *(const bf16x8*)(lds + 49152 + cur * 16384 + row * 128 +
                                           (((ks * 2 + hh) ^ (row & 7)) << 4));
            }
            #pragma unroll
            for (int mf = 0; mf < 3; ++mf)
                #pragma unroll
                for (int nf = 0; nf < 2; ++nf)
                    acc[mf][nf] = mfma32(af[mf], bfr[nf], acc[mf][nf]);
        }
        __syncthreads();
        cur ^= 1;
    }

    // stage bias into LDS (staging region is dead now)
    if (tid < 192) bias_s[tid] = bq[((tid >> 6) << 9) + n * 64 + (tid & 63)];
    __syncthreads();

    // ---- epilogue: scatter C into attention layouts ----
    #pragma unroll
    for (int mf = 0; mf < 3; ++mf) {
        const int m0 = wm * 96 + mf * 32;
        #pragma unroll
        for (int nf = 0; nf < 2; ++nf) {
            const int t = wn * 2 + nf;
            const f32x16 v = acc[mf][nf];
            if (m0 < 128) {
                // Q (m0<64) or K: store transposed [t][d][c], packed b64 quads
                const int base = (m0 < 64) ? QT0 : KT0;
                const int c0g  = (m0 & 63) >> 3;      // granule base
                const int d    = l31;
                #pragma unroll
                for (int p = 0; p < 4; ++p) {
                    float4 bb = *(const float4*)(bias_s + m0 + 8 * p + 4 * hh);
                    unsigned int u0 = cvtpk(v[4 * p]     + bb.x, v[4 * p + 1] + bb.y);
                    unsigned int u1 = cvtpk(v[4 * p + 2] + bb.z, v[4 * p + 3] + bb.w);
                    *(uint2*)(lds + base + t * 4096 + d * 128 +
                              (((c0g + p) ^ (d & 7)) << 4) + 8 * hh) = make_uint2(u0, u1);
                }
            } else {
                // V: store VT[e][j] WITHOUT bias (bias folded into PV epilogue)
                const int e0 = m0 - 128;
                const int j  = wn * 64 + nf * 32 + l31;
                #pragma unroll
                for (int reg = 0; reg < 16; ++reg) {
                    const int e = e0 + (reg & 3) + 8 * (reg >> 2) + 4 * hh;
                    unsigned int u = cvtpk(v[reg], v[reg]);
                    *(unsigned short*)(lds + VT0 + e * 256 +
                                       (((j >> 3) ^ (e & 7)) << 4) + ((2 * j) & 15)) =
                        (unsigned short)(u & 0xffffu);
                }
            }
        }
    }
    __syncthreads();

    // ---- attention: wave wv handles t = wv ----
    {
        const int t  = wv;
        const int qg = l >> 4;
        f32x4 sacc[2][2];
        sacc[0][0] = (f32x4)0.f; sacc[0][1] = (f32x4)0.f;
        sacc[1][0] = (f32x4)0.f; sacc[1][1] = (f32x4)0.f;
        #pragma unroll
        for (int kh = 0; kh < 2; ++kh) {
            bf16x8 qa[2], kb[2];
            #pragma unroll
            for (int mt = 0; mt < 2; ++mt) {
                const int i = mt * 16 + (l & 15);
                qa[mt] = *(const bf16x8*)(lds + QT0 + t * 4096 + i * 128 +
                                          (((kh * 4 + qg) ^ (i & 7)) << 4));
            }
            #pragma unroll
            for (int nt = 0; nt < 2; ++nt) {
                const int jj = nt * 16 + (l & 15);
                kb[nt] = *(const bf16x8*)(lds + KT0 + t * 4096 + jj * 128 +
                                          (((kh * 4 + qg) ^ (jj & 7)) << 4));
            }
            #pragma unroll
            for (int mt = 0; mt < 2; ++mt)
                #pragma unroll
                for (int nt = 0; nt < 2; ++nt)
                    sacc[mt][nt] = mfma16(qa[mt], kb[nt], sacc[mt][nt]);
        }
        // softmax over j; P -> LDS natural [i][j]
        #pragma unroll
        for (int mt = 0; mt < 2; ++mt) {
            #pragma unroll
            for (int reg = 0; reg < 4; ++reg) {
                float s0 = sacc[mt][0][reg] * 0.125f;
                float s1 = sacc[mt][1][reg] * 0.125f;
                float m = fmaxf(s0, s1);
                m = fmaxf(m, __shfl_xor(m, 1));
                m = fmaxf(m, __shfl_xor(m, 2));
                m = fmaxf(m, __shfl_xor(m, 4));
                m = fmaxf(m, __shfl_xor(m, 8));
                float p0 = __expf(s0 - m);
                float p1 = __expf(s1 - m);
                float ss = p0 + p1;
                ss += __shfl_xor(ss, 1);
                ss += __shfl_xor(ss, 2);
                ss += __shfl_xor(ss, 4);
                ss += __shfl_xor(ss, 8);
                float inv = 1.0f / ss;
                const int i = mt * 16 + 4 * qg + reg;
                #pragma unroll
                for (int nt = 0; nt < 2; ++nt) {
                    const int j = nt * 16 + (l & 15);
                    unsigned int u = cvtpk((nt ? p1 : p0) * inv, 0.f);
                    *(unsigned short*)(lds + P0 + t * 2048 + i * 64 +
                                       (((j >> 3) ^ (i & 3)) << 4) + ((2 * j) & 15)) =
                        (unsigned short)(u & 0xffffu);
                }
            }
        }
        asm volatile("s_waitcnt lgkmcnt(0)" ::: "memory");
        __builtin_amdgcn_sched_barrier(0);

        // PV transposed: outT[c][i] = sum_j VT[c][j] * P[i][j]
        f32x16 oa[2];
        oa[0] = (f32x16)0.f; oa[1] = (f32x16)0.f;
        #pragma unroll
        for (int ks = 0; ks < 2; ++ks) {
            bf16x8 pb = *(const bf16x8*)(lds + P0 + t * 2048 + l31 * 64 +
                                         (((ks * 2 + hh) ^ (l31 & 3)) << 4));
            #pragma unroll
            for (int cf = 0; cf < 2; ++cf) {
                const int c = cf * 32 + l31;
                bf16x8 vv = *(const bf16x8*)(lds + VT0 + c * 256 +
                                             (((t * 4 + ks * 2 + hh) ^ (c & 7)) << 4));
                oa[cf] = mfma32(vv, pb, oa[cf]);
            }
        }
        // ao store: row s = sbase + i*1024 + t, packed b64 c-quads (+V bias)
        const size_t srow = (size_t)(sbase + l31 * 1024 + t) * 512 + n * 64;
        #pragma unroll
        for (int cf = 0; cf < 2; ++cf) {
            #pragma unroll
            for (int p = 0; p < 4; ++p) {
                const int cb = cf * 32 + 8 * p + 4 * hh;
                float4 bb = *(const float4*)(bias_s + 128 + cb);
                unsigned int u0 = cvtpk(oa[cf][4 * p]     + bb.x, oa[cf][4 * p + 1] + bb.y);
                unsigned int u1 = cvtpk(oa[cf][4 * p + 2] + bb.z, oa[cf][4 * p + 3] + bb.w);
                *(uint2*)(ao + srow + cb) = make_uint2(u0, u1);
            }
        }
    }
}

// ======================= out-projection GEMM + bias + residual =======================
__global__ __launch_bounds__(256, 2)
void axial_out(const unsigned short* __restrict__ ao,  // [65536][512] bf16
               const unsigned short* __restrict__ wo,  // [512][512] bf16
               const float* __restrict__ bo,
               const float* __restrict__ x,
               float* __restrict__ out)
{
    __shared__ __align__(16) char lds[65536];
    const int bid = blockIdx.x;
    const int vid = (bid & 7) * 256 + (bid >> 3);
    const int mt_ = vid & 3;
    const int nt_ = vid >> 2;
    const int m_base = mt_ * 128;
    const int s_base = nt_ * 128;
    const int bb  = s_base >> 15;
    const int spl = s_base & 32767;
    const float* xblk = x + (size_t)bb * 16777216 + spl;
    float* oblk = out + (size_t)bb * 16777216 + spl;

    const int tid = threadIdx.x;
    const int wv  = tid >> 6;
    const int l   = tid & 63;
    const int l31 = l & 31;
    const int hh  = l >> 5;
    const int wm  = wv >> 1;
    const int wn  = wv & 1;

    auto stage = [&](int kk, int buf) {
        #pragma unroll
        for (int i = 0; i < 4; ++i) {
            const int il  = wv * 4 + i;
            const int row = il * 8 + (l >> 3);
            const unsigned short* srcA = wo + (m_base + row) * 512 + kk * 64 +
                                         (((l & 7) ^ (row & 7)) << 3);
            gload16(srcA, lds + buf * 16384 + il * 1024);
            const unsigned short* srcB = ao + (size_t)(s_base + row) * 512 + kk * 64 +
                                         (((l & 7) ^ (row & 7)) << 3);
            gload16(srcB, lds + 32768 + buf * 16384 + il * 1024);
        }
    };

    f32x16 acc[2][2];
    acc[0][0] = (f32x16)0.f; acc[0][1] = (f32x16)0.f;
    acc[1][0] = (f32x16)0.f; acc[1][1] = (f32x16)0.f;

    stage(0, 0);
    __syncthreads();
    int cur = 0;
    for (int kk = 0; kk < 8; ++kk) {
        if (kk < 7) stage(kk + 1, cur ^ 1);
        #pragma unroll
        for (int ks = 0; ks < 4; ++ks) {
            bf16x8 af[2], bfr[2];
            #pragma unroll
            for (int mf = 0; mf < 2; ++mf) {
                const int row = wm * 64 + mf * 32 + l31;
                af[mf] = *(const bf16x8*)(lds + cur * 16384 + row * 128 +
                                          (((ks * 2 + hh) ^ (row & 7)) << 4));
            }
            #pragma unroll
            for (int nf = 0; nf < 2; ++nf) {
                const int row = wn * 64 + nf * 32 + l31;
                bfr[nf] = *(const bf16x8*)(lds + 32768 + cur * 16384 + row * 128 +
                                           (((ks * 2 + hh) ^ (row & 7)) << 4));
            }
            #pragma unroll
            for (int mf = 0; mf < 2; ++mf)
                #pragma unroll
                for (int nf = 0; nf < 2; ++nf)
                    acc[mf][nf] = mfma32(af[mf], bfr[nf], acc[mf][nf]);
        }
        __syncthreads();
        cur ^= 1;
    }

    // epilogue: + bias + residual, fp32 stores
    #pragma unroll
    for (int mf = 0; mf < 2; ++mf) {
        #pragma unroll
        for (int reg = 0; reg < 16; ++reg) {
            const int co = m_base + wm * 64 + mf * 32 + (reg & 3) + 8 * (reg >> 2) + 4 * hh;
            const float bias = bo[co];
            #pragma unroll
            for (int nf = 0; nf < 2; ++nf) {
                const int sl = wn * 64 + nf * 32 + l31;
                oblk[(size_t)co * 32768 + sl] = acc[mf][nf][reg] + bias +
                                                xblk[(size_t)co * 32768 + sl];
            }
        }
    }
}

// ======================= round-2 fallback (fully fused) =======================
__device__ __forceinline__ int adr_qk(int row, int cb) { return row * 2048 + (cb ^ ((row & 7) << 4)); }
__device__ __forceinline__ int adr_x (int row, int cb) { return 98304 + row * 1024 + (cb ^ ((row & 7) << 4)); }
__device__ __forceinline__ int adr_xl(int row, int cb) { return 131072 + row * 1024 + (cb ^ ((row & 7) << 4)); }
__device__ __forceinline__ int adr_v (int e, int jb)   { int a = e * 64 + jb; return 65536 + (a ^ ((e & 7) << 4)); }

__global__ __launch_bounds__(512, 1)
void axial3d_mfma(const float* __restrict__ x,
                  const float* __restrict__ bq,
                  const float* __restrict__ bo,
                  const unsigned short* __restrict__ wq,
                  const unsigned short* __restrict__ wo,
                  float* __restrict__ out) {
    __shared__ char lds[163840];
    const int bid  = blockIdx.x;
    const int work = (bid & 7) * 256 + (bid >> 3);
    const int b    = work >> 10;
    const int h    = (work >> 5) & 31;
    const int w    = work & 31;
    const float* xb = x   + ((size_t)b * 16777216u) + h * 32 + w;
    float*       ob = out + ((size_t)b * 16777216u) + h * 32 + w;
    const int tid  = threadIdx.x;
    const int wv   = tid >> 6;
    const int lane = tid & 63;
    const int g    = lane >> 4;
    const int q    = lane & 15;
    {
        const int d  = tid & 31;
        const int c0 = tid >> 5;
        #pragma unroll
        for (int it = 0; it < 32; ++it) {
            int c = c0 + it * 16;
            float xv = xb[c * 32768 + d * 1024];
            unsigned short hi = f2b(xv);
            unsigned short lo = f2b(xv - b2f(hi));
            *(unsigned short*)(lds + adr_x(d, c * 2))  = hi;
            *(unsigned short*)(lds + adr_xl(d, c * 2)) = lo;
        }
    }
    __syncthreads();
    for (int tp = 0; tp < 3; ++tp) {
        const int mt0 = wv * 12 + tp * 4;
        f32x4 acc[4][2];
        #pragma unroll
        for (int t = 0; t < 4; ++t) { acc[t][0] = (f32x4)0.f; acc[t][1] = (f32x4)0.f; }
        #pragma unroll
        for (int kk = 0; kk < 16; ++kk) {
            bf16x8 bfr[2];
            #pragma unroll
            for (int nt = 0; nt < 2; ++nt)
                bfr[nt] = *(const bf16x8*)(lds + adr_x(nt * 16 + q, kk * 64 + g * 16));
            #pragma unroll
            for (int t = 0; t < 4; ++t) {
                const int o = (mt0 + t) * 16 + q;
                bf16x8 a = *(const bf16x8*)((const char*)wq + o * 1024 + kk * 64 + g * 16);
                acc[t][0] = mfma16(a, bfr[0], acc[t][0]);
                acc[t][1] = mfma16(a, bfr[1], acc[t][1]);
            }
        }
        #pragma unroll
        for (int t = 0; t < 4; ++t) {
            const int mt    = mt0 + t;
            const int obase = mt * 16 + 4 * g;
            float bias[4];
            #pragma unroll
            for (int r = 0; r < 4; ++r) bias[r] = bq[obase + r];
            if (mt < 64) {
                #pragma unroll
                for (int nt = 0; nt < 2; ++nt) {
                    const int d = nt * 16 + q;
                    unsigned int lo = f2b(acc[t][nt][0] + bias[0]) |
                                      ((unsigned int)f2b(acc[t][nt][1] + bias[1]) << 16);
                    unsigned int hi = f2b(acc[t][nt][2] + bias[2]) |
                                      ((unsigned int)f2b(acc[t][nt][3] + bias[3]) << 16);
                    *(uint2*)(lds + adr_qk(d, obase * 2)) = make_uint2(lo, hi);
                }
            } else {
                #pragma unroll
                for (int nt = 0; nt < 2; ++nt) {
                    const int d = nt * 16 + q;
                    #pragma unroll
                    for (int r = 0; r < 4; ++r) {
                        const int e = obase + r - 1024;
                        *(unsigned short*)(lds + adr_v(e, d * 2)) = f2b(acc[t][nt][r] + bias[r]);
                    }
                }
            }
        }
    }
    __syncthreads();
    {
        const int n = wv;
        f32x4 s[2][2];
        s[0][0] = (f32x4)0.f; s[0][1] = (f32x4)0.f;
        s[1][0] = (f32x4)0.f; s[1][1] = (f32x4)0.f;
        #pragma unroll
        for (int kk = 0; kk < 2; ++kk) {
            bf16x8 a0 = *(const bf16x8*)(lds + adr_qk(q,      n * 128 + kk * 64 + g * 16));
            bf16x8 a1 = *(const bf16x8*)(lds + adr_qk(16 + q, n * 128 + kk * 64 + g * 16));
            bf16x8 b0 = *(const bf16x8*)(lds + adr_qk(q,      1024 + n * 128 + kk * 64 + g * 16));
            bf16x8 b1 = *(const bf16x8*)(lds + adr_qk(16 + q, 1024 + n * 128 + kk * 64 + g * 16));
            s[0][0] = mfma16(a0, b0, s[0][0]);
            s[0][1] = mfma16(a0, b1, s[0][1]);
            s[1][0] = mfma16(a1, b0, s[1][0]);
            s[1][1] = mfma16(a1, b1, s[1][1]);
        }
        float pv[2][2][4];
        #pragma unroll
        for (int it = 0; it < 2; ++it) {
            #pragma unroll
            for (int r = 0; r < 4; ++r) {
                float s0 = s[it][0][r] * 0.125f;
                float s1 = s[it][1][r] * 0.125f;
                float m = fmaxf(s0, s1);
                m = fmaxf(m, __shfl_xor(m, 1));
                m = fmaxf(m, __shfl_xor(m, 2));
                m = fmaxf(m, __shfl_xor(m, 4));
                m = fmaxf(m, __shfl_xor(m, 8));
                float p0 = __expf(s0 - m);
                float p1 = __expf(s1 - m);
                float ss = p0 + p1;
                ss += __shfl_xor(ss, 1);
                ss += __shfl_xor(ss, 2);
                ss += __shfl_xor(ss, 4);
                ss += __shfl_xor(ss, 8);
                float inv = 1.0f / ss;
                pv[it][0][r] = p0 * inv;
                pv[it][1][r] = p1 * inv;
            }
        }
        #pragma unroll
        for (int it = 0; it < 2; ++it)
            #pragma unroll
            for (int jt = 0; jt < 2; ++jt)
                #pragma unroll
                for (int r = 0; r < 4; ++r) {
                    const int i = it * 16 + 4 * g + r;
                    *(unsigned short*)(lds + adr_qk(i, n * 128 + (jt * 16 + q) * 2)) =
                        f2b(pv[it][jt][r]);
                }
        asm volatile("s_waitcnt lgkmcnt(0)" ::: "memory");
        __builtin_amdgcn_sched_barrier(0);
        bf16x8 pa0 = *(const bf16x8*)(lds + adr_qk(q,      n * 128 + g * 16));
        bf16x8 pa1 = *(const bf16x8*)(lds + adr_qk(16 + q, n * 128 + g * 16));
        #pragma unroll
        for (int et = 0; et < 4; ++et) {
            const int e = n * 64 + et * 16 + q;
            bf16x8 vb = *(const bf16x8*)(lds + adr_v(e, g * 16));
            f32x4 o0 = mfma16(pa0, vb, (f32x4)0.f);
            f32x4 o1 = mfma16(pa1, vb, (f32x4)0.f);
            const int cb = 1024 + n * 128 + (et * 16 + q) * 2;
            #pragma unroll
            for (int r = 0; r < 4; ++r) {
                *(unsigned short*)(lds + adr_qk(4 * g + r, cb))      = f2b(o0[r]);
                *(unsigned short*)(lds + adr_qk(16 + 4 * g + r, cb)) = f2b(o1[r]);
            }
        }
    }
    __syncthreads();
    for (int p4 = 0; p4 < 4; ++p4) {
        const int mt = wv * 4 + p4;
        f32x4 acc[2];
        acc[0] = (f32x4)0.f; acc[1] = (f32x4)0.f;
        #pragma unroll
        for (int kk = 0; kk < 16; ++kk) {
            bf16x8 b0 = *(const bf16x8*)(lds + adr_qk(q,      1024 + kk * 64 + g * 16));
            bf16x8 b1 = *(const bf16x8*)(lds + adr_qk(16 + q, 1024 + kk * 64 + g * 16));
            bf16x8 a  = *(const bf16x8*)((const char*)wo + (mt * 16 + q) * 1024 + kk * 64 + g * 16);
            acc[0] = mfma16(a, b0, acc[0]);
            acc[1] = mfma16(a, b1, acc[1]);
        }
        const int obase = mt * 16 + 4 * g;
        float bias[4];
        #pragma unroll
        for (int r = 0; r < 4; ++r) bias[r] = bo[obase + r];
        #pragma unroll
        for (int nt = 0; nt < 2; ++nt) {
            const int d = nt * 16 + q;
            uint2 xh = *(const uint2*)(lds + adr_x(d, obase * 2));
            uint2 xl = *(const uint2*)(lds + adr_xl(d, obase * 2));
            float res[4];
            res[0] = b2f(xh.x & 0xffffu) + b2f(xl.x & 0xffffu);
            res[1] = b2f(xh.x >> 16)     + b2f(xl.x >> 16);
            res[2] = b2f(xh.y & 0xffffu) + b2f(xl.y & 0xffffu);
            res[3] = b2f(xh.y >> 16)     + b2f(xl.y >> 16);
            #pragma unroll
            for (int r = 0; r < 4; ++r)
                ob[(obase + r) * 32768 + d * 1024] = acc[nt][r] + bias[r] + res[r];
        }
    }
}

// ======================= launch =======================
extern "C" void kernel_launch(void* const* d_in, const int* in_sizes, int n_in,
                              void* d_out, int out_size, void* d_ws, size_t ws_size,
                              hipStream_t stream) {
    const float* x     = (const float*)d_in[0];
    const float* w_qkv = (const float*)d_in[1];
    const float* b_qkv = (const float*)d_in[2];
    const float* w_out = (const float*)d_in[3];
    const float* b_out = (const float*)d_in[4];
    float* out = (float*)d_out;

    const size_t XT_OFF = 0;                 // 64 MB bf16 [65536][512]
    const size_t AO_OFF = 67108864;          // 64 MB bf16 [65536][512]
    const size_t WQ_OFF = 134217728;         // 2 MB bf16 weights
    const size_t NEED   = 136314880;

    if (ws_size >= NEED) {
        unsigned short* xT  = (unsigned short*)((char*)d_ws + XT_OFF);
        unsigned short* ao  = (unsigned short*)((char*)d_ws + AO_OFF);
        unsigned short* wbf = (unsigned short*)((char*)d_ws + WQ_OFF);
        xprep   <<<dim3(2304), dim3(256), 0, stream>>>(x, w_qkv, w_out, xT, wbf);
        axial_ab<<<dim3(4096), dim3(256), 0, stream>>>(xT, wbf, b_qkv, ao);
        axial_out<<<dim3(2048), dim3(256), 0, stream>>>(ao, wbf + 786432, b_out, x, out);
    } else {
        unsigned short* wbf = (unsigned short*)d_ws;
        // fallback needs the old wconvert path folded in: reuse xprep's weight part only
        xprep<<<dim3(2304), dim3(256), 0, stream>>>(x, (const float*)d_in[1], w_out,
                                                    (unsigned short*)d_ws, wbf);
        axial3d_mfma<<<dim3(2048), dim3(512), 0, stream>>>(x, b_qkv, b_out,
                                                           wbf, wbf + 786432, out);
    }
}